// Round 3
// baseline (164.498 us; speedup 1.0000x reference)
//
#include <hip/hip_runtime.h>
#include <hip/hip_bf16.h>

// Problem constants
#define BATCH  16384
#define GATES  1023
#define NPAD   1024
#define OUTF   128

typedef unsigned short ushortT;
typedef short bf16x8 __attribute__((ext_vector_type(8)));
typedef float f32x4 __attribute__((ext_vector_type(4)));

__device__ inline float bf2f(ushortT u) {
    union { unsigned int i; float f; } v;
    v.i = ((unsigned int)u) << 16;
    return v.f;
}
__device__ inline ushortT f2bf(float f) {
    union { float f; unsigned int i; } v;
    v.f = f;
    unsigned int x = v.i;
    unsigned int r = (x + 0x7FFFu + ((x >> 16) & 1u)) >> 16;  // RNE
    return (ushortT)r;
}
// packed f32 pair -> bf16 pair (RNE); compiler lowers to v_cvt_pk_bf16_f32.
__device__ inline unsigned pkbf(float lo, float hi) {
    __hip_bfloat162 h = __float22bfloat162_rn(float2{lo, hi});
    union { __hip_bfloat162 h; unsigned u; } c;
    c.h = h;
    return c.u;
}
// Row-XOR on ushort-index bits 3..5 (16B-slot bits 0..2). Spreads accesses
// where lanes touch DIFFERENT rows simultaneously (P1 epilogue quads, P3
// A-reads). Row-uniform phases (P2) are made conflict-free by layout instead:
// gate g lives at slot (g+1)^x8 -> deep-tree reads become stride-16B vector
// reads; slot x8 (the image of 0) is the hole that absorbs pad col 1023.
__device__ inline int swz8(int row) { return (((row ^ (row >> 3)) & 7) << 3); }

// ---------------- prep: gwT (tiled transpose+pad), zh, gbp ----------------
__global__ __launch_bounds__(256) void k_prep(const float* __restrict__ gw,
                                              const float* __restrict__ gb,
                                              const float* __restrict__ z,
                                              ushortT* __restrict__ gwT,
                                              float* __restrict__ gbp,
                                              ushortT* __restrict__ zh) {
    const int b = blockIdx.x, t = threadIdx.x;
    if (b < 64) {
        __shared__ ushortT tile[64][65];  // pad 65: transposed reads conflict-free
        const int k0 = (b >> 4) * 64, n0 = (b & 15) * 64;
        const int tr = t >> 6, tc = t & 63;
#pragma unroll
        for (int p = 0; p < 16; ++p) {
            int k = p * 4 + tr;
            int n = n0 + tc;
            float v = (n < GATES) ? gw[(size_t)(k0 + k) * GATES + n] : 0.f;
            tile[k][tc] = f2bf(v);
        }
        __syncthreads();
#pragma unroll
        for (int p = 0; p < 2; ++p) {
            int nn = (t >> 3) + p * 32;
            int ks = (t & 7) * 8;
            ushortT o[8];
#pragma unroll
            for (int u = 0; u < 8; ++u) o[u] = tile[ks + u][nn];
            *(bf16x8*)(gwT + (size_t)(n0 + nn) * 256 + k0 + ks) = *(bf16x8*)o;
        }
    } else if (b < 128) {
        int i = (b - 64) * 256 + t;
        const float4* p = (const float4*)z + (size_t)i * 2;
        float4 a = p[0], c = p[1];
        union { unsigned u[4]; bf16x8 v; } o;
        o.u[0] = pkbf(a.x, a.y); o.u[1] = pkbf(a.z, a.w);
        o.u[2] = pkbf(c.x, c.y); o.u[3] = pkbf(c.z, c.w);
        *(bf16x8*)(zh + (size_t)i * 8) = o.v;
    } else {
#pragma unroll
        for (int u = 0; u < 4; ++u) {
            int id = t * 4 + u;
            gbp[id] = (id < GATES) ? gb[id] : 0.f;
        }
    }
}

// ---------------- mega: x -> gatings -> leaves -> out, one block = 32 rows ----
// B operands (gwT, zh) are 16B-contiguous per lane in global and L2-resident
// (512KB+256KB): loaded DIRECTLY into registers -> no sS staging, no per-tile
// barriers. Only 2 __syncthreads in the whole kernel (P1->P2, P2->P3).
// LDS = sG 64KB only -> 2 blocks/CU.
__global__ __launch_bounds__(256) void k_mega(const float* __restrict__ x,
                                              const ushortT* __restrict__ gwT,
                                              const float* __restrict__ gbp,
                                              const ushortT* __restrict__ zh,
                                              float* __restrict__ out) {
    __shared__ __align__(16) ushortT sG[32 * 1024];  // 64 KB

    const int tid = threadIdx.x;
    const int wave = tid >> 6, lane = tid & 63;
    const int quad = lane >> 4, l15 = lane & 15;
    const int wr = wave >> 1, wc = wave & 1;   // 2x2 wave grid; wave tile 16x64
    const int bm = blockIdx.x * 32;

    // ---- preload A: x rows (f32) -> bf16 MFMA fragments, af[c] covers k=c*32+quad*8
    bf16x8 af[8];
    {
        const float* xr = x + (size_t)(bm + wr * 16 + l15) * 256;
#pragma unroll
        for (int c = 0; c < 8; ++c) {
            const float4* p = (const float4*)(xr + c * 32 + quad * 8);
            float4 a = p[0], b = p[1];
            union { unsigned u[4]; bf16x8 v; } o;
            o.u[0] = pkbf(a.x, a.y); o.u[1] = pkbf(a.z, a.w);
            o.u[2] = pkbf(b.x, b.y); o.u[3] = pkbf(b.z, b.w);
            af[c] = o.v;
        }
    }

    // epilogue row constants (C/D: col=l15, row=quad*4+reg)
    const int row0 = wr * 16 + quad * 4;
    int eb[4], ex[4];
#pragma unroll
    for (int r = 0; r < 4; ++r) {
        eb[r] = (row0 + r) << 10;
        ex[r] = swz8(row0 + r);
    }

    // per-lane B base: row (wc*64+l15), k-offset quad*8
    const ushortT* gwB = gwT + (size_t)(wc * 64 + l15) * 256 + quad * 8;

    // ---- P1: gatings = sigmoid(x @ gw + gb), B-frags direct from global ----
    for (int n0 = 0; n0 < 1024; n0 += 128) {
        f32x4 acc[4] = {};
#pragma unroll
        for (int k0 = 0; k0 < 256; k0 += 64) {
#pragma unroll
            for (int ks = 0; ks < 2; ++ks) {
                bf16x8 a0 = af[(k0 >> 5) + ks];
#pragma unroll
                for (int j = 0; j < 4; ++j) {
                    bf16x8 b0 = *(const bf16x8*)(gwB + (size_t)(n0 + j * 16) * 256 +
                                                 k0 + ks * 32);
                    acc[j] = __builtin_amdgcn_mfma_f32_16x16x32_bf16(a0, b0, acc[j], 0, 0, 0);
                }
            }
        }
        // epilogue: sigmoid -> sG; gate col stored at slot ((col+1)&1023)^x8
        // (pad col 1023 -> slot 0 -> position x8, the unique unused hole)
#pragma unroll
        for (int j = 0; j < 4; ++j) {
            int col = n0 + wc * 64 + j * 16 + l15;
            float bs = gbp[col];
            float g0 = 1.f / (1.f + __expf(-(acc[j][0] + bs)));
            float g1 = 1.f / (1.f + __expf(-(acc[j][1] + bs)));
            float g2 = 1.f / (1.f + __expf(-(acc[j][2] + bs)));
            float g3 = 1.f / (1.f + __expf(-(acc[j][3] + bs)));
            unsigned p0 = pkbf(g0, g1), p1 = pkbf(g2, g3);
            int s = (col + 1) & 1023;
            sG[eb[0] + (s ^ ex[0])] = (ushortT)p0;
            sG[eb[1] + (s ^ ex[1])] = (ushortT)(p0 >> 16);
            sG[eb[2] + (s ^ ex[2])] = (ushortT)p1;
            sG[eb[3] + (s ^ ex[3])] = (ushortT)(p1 >> 16);
        }
    }
    __syncthreads();

    // ---- P2: tree; deep levels via conflict-free vector reads ----
    {
        const int r0 = wave * 8;
        for (int rr = 0; rr < 8; ++rr) {
            const int row = r0 + rr;
            const int rowb = row << 10;
            const int x8 = swz8(row);
            float P = 1.f;
#pragma unroll
            for (int d = 0; d < 6; ++d) {
                int slot = (1 << d) + (lane >> (6 - d));   // gate (1<<d)-1 + ...
                float g = bf2f(sG[rowb + (slot ^ x8)]);
                int bit = (lane >> (5 - d)) & 1;
                P *= bit ? (1.f - g) : g;
            }
            // level 6: gate 63+lane (u16, stride-2B: free)
            float g6 = bf2f(sG[rowb + ((64 + lane) ^ x8)]);
            float va = P * g6, vb = P - va;
            // level 7: gates 127+2L,128+2L (b32, coalesced)
            unsigned w7 = *(const unsigned*)(sG + rowb + ((128 + 2 * lane) ^ x8));
            float v4[4];
            {
                float ga = bf2f((ushortT)w7), gbv = bf2f((ushortT)(w7 >> 16));
                v4[0] = va * ga;  v4[1] = va - v4[0];
                v4[2] = vb * gbv; v4[3] = vb - v4[2];
            }
            // level 8: gates 255+4L..+4 (b64, coalesced)
            const unsigned* p8 = (const unsigned*)(sG + rowb + ((256 + 4 * lane) ^ x8));
            unsigned w8a = p8[0], w8b = p8[1];
            float v8[8];
            {
                float h0 = bf2f((ushortT)w8a), h1 = bf2f((ushortT)(w8a >> 16));
                float h2 = bf2f((ushortT)w8b), h3 = bf2f((ushortT)(w8b >> 16));
                v8[0] = v4[0] * h0; v8[1] = v4[0] - v8[0];
                v8[2] = v4[1] * h1; v8[3] = v4[1] - v8[2];
                v8[4] = v4[2] * h2; v8[5] = v4[2] - v8[4];
                v8[6] = v4[3] * h3; v8[7] = v4[3] - v8[6];
            }
            // level 9: gates 511+8L..+8 (b128, lane->consecutive 16B slots)
            bf16x8 g9 = *(const bf16x8*)(sG + rowb + ((512 + 8 * lane) ^ x8));
            float v16[16];
#pragma unroll
            for (int t = 0; t < 8; ++t) {
                float g = bf2f((ushortT)g9[t]);
                float a = v8[t] * g;
                v16[2 * t] = a;
                v16[2 * t + 1] = v8[t] - a;
            }
            // leaves: block 2L (leaves 16L..+8) -> slot L^x; block 2L+1 -> 64+(L^x)
            // both b128 writes stride-16B conflict-free; row-local => in-place safe.
            union { unsigned u[4]; bf16x8 v; } q0, q1;
#pragma unroll
            for (int t = 0; t < 4; ++t) q0.u[t] = pkbf(v16[2 * t], v16[2 * t + 1]);
#pragma unroll
            for (int t = 0; t < 4; ++t) q1.u[t] = pkbf(v16[8 + 2 * t], v16[9 + 2 * t]);
            int a0u = rowb + ((lane << 3) ^ x8);
            *(bf16x8*)(sG + a0u) = q0.v;
            *(bf16x8*)(sG + a0u + 512) = q1.v;
        }
    }
    __syncthreads();

    // ---- P3: out = leaf @ z^T; A from sG, B direct from zh (global/L2) ----
    f32x4 acc[4] = {};
    const int rowA = wr * 16 + l15;
    const int rowbA = rowA << 10;
    const int xA8 = swz8(rowA);
    const ushortT* zB = zh + (size_t)(wc * 64 + l15) * 1024 + quad * 8;
#pragma unroll 2
    for (int k0 = 0; k0 < 1024; k0 += 64) {
#pragma unroll
        for (int ks = 0; ks < 2; ++ks) {
            int b = (k0 >> 3) + 4 * ks + quad;  // leaf block index
            int us = ((b & 1) << 9) + ((((b >> 1) << 3)) ^ xA8);
            bf16x8 a0 = *(const bf16x8*)(sG + rowbA + us);
#pragma unroll
            for (int j = 0; j < 4; ++j) {
                bf16x8 b0 = *(const bf16x8*)(zB + (size_t)(j * 16) * 1024 +
                                             k0 + ks * 32);
                acc[j] = __builtin_amdgcn_mfma_f32_16x16x32_bf16(a0, b0, acc[j], 0, 0, 0);
            }
        }
    }
    const int gm = bm + wr * 16 + quad * 4;
#pragma unroll
    for (int j = 0; j < 4; ++j) {
        int gn = wc * 64 + j * 16 + l15;
#pragma unroll
        for (int r = 0; r < 4; ++r)
            out[(size_t)(gm + r) * OUTF + gn] = acc[j][r];
    }
}

// ---------------- launch ----------------
extern "C" void kernel_launch(void* const* d_in, const int* in_sizes, int n_in,
                              void* d_out, int out_size, void* d_ws, size_t ws_size,
                              hipStream_t stream) {
    const float* x  = (const float*)d_in[0];   // 16384 x 256
    const float* gw = (const float*)d_in[1];   // 256 x 1023
    const float* gb = (const float*)d_in[2];   // 1023
    const float* z  = (const float*)d_in[3];   // 128 x 1024
    float* out = (float*)d_out;                // 16384 x 128

    char* ws = (char*)d_ws;
    ushortT* gwT = (ushortT*)(ws + 0);       // 524,288 B
    ushortT* zh  = (ushortT*)(ws + 524288);  // 262,144 B
    float*   gbp = (float*)  (ws + 786432);  //   4,096 B (total < 1 MB)

    k_prep<<<129, 256, 0, stream>>>(gw, gb, z, gwT, gbp, zh);
    k_mega<<<512, 256, 0, stream>>>(x, gwT, gbp, zh, out);
}

// Round 4
// 120.642 us; speedup vs baseline: 1.3635x; 1.3635x over previous
//
#include <hip/hip_runtime.h>
#include <hip/hip_bf16.h>

// Problem constants
#define BATCH  16384
#define GATES  1023
#define NPAD   1024
#define OUTF   128

typedef unsigned short ushortT;
typedef short bf16x8 __attribute__((ext_vector_type(8)));
typedef float f32x4 __attribute__((ext_vector_type(4)));

__device__ inline float bf2f(ushortT u) {
    union { unsigned int i; float f; } v;
    v.i = ((unsigned int)u) << 16;
    return v.f;
}
__device__ inline ushortT f2bf(float f) {
    union { float f; unsigned int i; } v;
    v.f = f;
    unsigned int x = v.i;
    unsigned int r = (x + 0x7FFFu + ((x >> 16) & 1u)) >> 16;  // RNE
    return (ushortT)r;
}
// packed f32 pair -> bf16 pair (RNE); compiler lowers to v_cvt_pk_bf16_f32.
__device__ inline unsigned pkbf(float lo, float hi) {
    __hip_bfloat162 h = __float22bfloat162_rn(float2{lo, hi});
    union { __hip_bfloat162 h; unsigned u; } c;
    c.h = h;
    return c.u;
}
// Row-XOR on ushort-index bits 3..5 (16B-slot bits 0..2). Spreads accesses
// where lanes touch DIFFERENT rows simultaneously (P1 epilogue quads, P3
// A-reads). Row-uniform P2 is conflict-free by layout: gate g lives at slot
// (g+1)^x8 -> deep-tree reads become stride-16B vector reads; slot x8 (image
// of 0) is the hole absorbing pad col 1023.  [R3-measured: 4.59M -> 262K]
__device__ inline int swz8(int row) { return (((row ^ (row >> 3)) & 7) << 3); }

// async global->LDS, 16B/lane; lds base wave-uniform, HW writes base + lane*16.
__device__ inline void gl2lds16(const void* gptr, void* ldsptr) {
    __builtin_amdgcn_global_load_lds(
        (const __attribute__((address_space(1))) void*)gptr,
        (__attribute__((address_space(3))) void*)ldsptr, 16, 0, 0);
}

// ---------------- prep: gwT (tiled transpose+pad), zh, gbp ----------------
__global__ __launch_bounds__(256) void k_prep(const float* __restrict__ gw,
                                              const float* __restrict__ gb,
                                              const float* __restrict__ z,
                                              ushortT* __restrict__ gwT,
                                              float* __restrict__ gbp,
                                              ushortT* __restrict__ zh) {
    const int b = blockIdx.x, t = threadIdx.x;
    if (b < 64) {
        __shared__ ushortT tile[64][65];  // pad 65: transposed reads conflict-free
        const int k0 = (b >> 4) * 64, n0 = (b & 15) * 64;
        const int tr = t >> 6, tc = t & 63;
#pragma unroll
        for (int p = 0; p < 16; ++p) {
            int k = p * 4 + tr;
            int n = n0 + tc;
            float v = (n < GATES) ? gw[(size_t)(k0 + k) * GATES + n] : 0.f;
            tile[k][tc] = f2bf(v);
        }
        __syncthreads();
#pragma unroll
        for (int p = 0; p < 2; ++p) {
            int nn = (t >> 3) + p * 32;
            int ks = (t & 7) * 8;
            ushortT o[8];
#pragma unroll
            for (int u = 0; u < 8; ++u) o[u] = tile[ks + u][nn];
            *(bf16x8*)(gwT + (size_t)(n0 + nn) * 256 + k0 + ks) = *(bf16x8*)o;
        }
    } else if (b < 128) {
        int i = (b - 64) * 256 + t;
        const float4* p = (const float4*)z + (size_t)i * 2;
        float4 a = p[0], c = p[1];
        union { unsigned u[4]; bf16x8 v; } o;
        o.u[0] = pkbf(a.x, a.y); o.u[1] = pkbf(a.z, a.w);
        o.u[2] = pkbf(c.x, c.y); o.u[3] = pkbf(c.z, c.w);
        *(bf16x8*)(zh + (size_t)i * 8) = o.v;
    } else {
#pragma unroll
        for (int u = 0; u < 4; ++u) {
            int id = t * 4 + u;
            gbp[id] = (id < GATES) ? gb[id] : 0.f;
        }
    }
}

// ---------------- mega: x -> gatings -> leaves -> out, one block = 32 rows ----
// LDS: sG 64KB gate/leaf buffer (R3 layout), sS 2x8KB double-buffered staging.
// 80KB -> 2 blocks/CU (cross-block overlap of barrier drains).
// Per 8KB tile (128 rows x 32 k bf16): STAGE(next) || MFMA(cur) -> one
// __syncthreads per tile (T3 minimum 2-phase recipe): prefetch latency hides
// under current tile's ds_read+MFMA; the barrier's vmcnt(0) drains only the
// remainder. Overwrite-safe: stage t+1 targets the buffer last read at t-1,
// all waves passed t-1's barrier before any wave enters iter t.
__global__ __launch_bounds__(256) void k_mega(const float* __restrict__ x,
                                              const ushortT* __restrict__ gwT,
                                              const float* __restrict__ gbp,
                                              const ushortT* __restrict__ zh,
                                              float* __restrict__ out) {
    __shared__ __align__(16) ushortT sG[32 * 1024];  // 64 KB
    __shared__ __align__(16) ushortT sS[2][4096];    // 2 x 8 KB

    const int tid = threadIdx.x;
    const int wave = tid >> 6, lane = tid & 63;
    const int quad = lane >> 4, l15 = lane & 15;
    const int wr = wave >> 1, wc = wave & 1;   // 2x2 wave grid; wave tile 16x64
    const int bm = blockIdx.x * 32;
    const int srow = lane >> 2;                // staging row within 16-row group
    const int scol = (lane & 3) * 8;           // staging elem col within 32

    // ---- preload A: x rows (f32) -> bf16 MFMA fragments, af[c] covers k=c*32+quad*8
    bf16x8 af[8];
    {
        const float* xr = x + (size_t)(bm + wr * 16 + l15) * 256;
#pragma unroll
        for (int c = 0; c < 8; ++c) {
            const float4* p = (const float4*)(xr + c * 32 + quad * 8);
            float4 a = p[0], b = p[1];
            union { unsigned u[4]; bf16x8 v; } o;
            o.u[0] = pkbf(a.x, a.y); o.u[1] = pkbf(a.z, a.w);
            o.u[2] = pkbf(b.x, b.y); o.u[3] = pkbf(b.z, b.w);
            af[c] = o.v;
        }
    }

    // epilogue row constants (C/D: col=l15, row=quad*4+reg)
    const int row0 = wr * 16 + quad * 4;
    int eb[4], ex[4];
#pragma unroll
    for (int r = 0; r < 4; ++r) {
        eb[r] = (row0 + r) << 10;
        ex[r] = swz8(row0 + r);
    }

    // per-lane staging source bases
    const ushortT* gS = gwT + (size_t)srow * 256 + scol;
    const ushortT* zS = zh + (size_t)srow * 1024 + scol;

    // ---- P1: gatings = sigmoid(x @ gw + gb); 64 tiles of 128n x 32k ----
    // tile t: n0 = (t>>3)*128, kt = (t&7)*32; buf = t&1
    {
        // prologue: stage tile 0 into buf 0
#pragma unroll
        for (int r = 0; r < 2; ++r) {
            int e = wave * 2 + r;
            gl2lds16(gS + (size_t)(e * 16) * 256, &sS[0][e * 512]);
        }
        __syncthreads();

        for (int g = 0; g < 8; ++g) {          // n0 group
            f32x4 acc[4] = {};
#pragma unroll
            for (int s = 0; s < 8; ++s) {      // k tile (static)
                // prefetch tile t+1 into buf (s&1)^1
                if (g * 8 + s < 63) {
                    int tn = g * 8 + s + 1;
                    int n1 = (tn >> 3) << 7, k1 = (tn & 7) << 5;
#pragma unroll
                    for (int r = 0; r < 2; ++r) {
                        int e = wave * 2 + r;
                        gl2lds16(gS + (size_t)(n1 + e * 16) * 256 + k1,
                                 &sS[(s & 1) ^ 1][e * 512]);
                    }
                }
                bf16x8 a0 = af[s];
                __builtin_amdgcn_s_setprio(1);
#pragma unroll
                for (int j = 0; j < 4; ++j) {
                    bf16x8 b0 = *(const bf16x8*)(&sS[s & 1][(wc * 64 + j * 16 + l15) * 32 +
                                                           quad * 8]);
                    acc[j] = __builtin_amdgcn_mfma_f32_16x16x32_bf16(a0, b0, acc[j], 0, 0, 0);
                }
                __builtin_amdgcn_s_setprio(0);
                if (s == 7) {
                    // epilogue: sigmoid -> sG; gate col at slot ((col+1)&1023)^x8
                    int n0 = g << 7;
#pragma unroll
                    for (int j = 0; j < 4; ++j) {
                        int col = n0 + wc * 64 + j * 16 + l15;
                        float bs = gbp[col];
                        float g0 = 1.f / (1.f + __expf(-(acc[j][0] + bs)));
                        float g1 = 1.f / (1.f + __expf(-(acc[j][1] + bs)));
                        float g2 = 1.f / (1.f + __expf(-(acc[j][2] + bs)));
                        float g3 = 1.f / (1.f + __expf(-(acc[j][3] + bs)));
                        unsigned p0 = pkbf(g0, g1), p1 = pkbf(g2, g3);
                        int sl = (col + 1) & 1023;
                        sG[eb[0] + (sl ^ ex[0])] = (ushortT)p0;
                        sG[eb[1] + (sl ^ ex[1])] = (ushortT)(p0 >> 16);
                        sG[eb[2] + (sl ^ ex[2])] = (ushortT)p1;
                        sG[eb[3] + (sl ^ ex[3])] = (ushortT)(p1 >> 16);
                    }
                }
                __syncthreads();
            }
        }
    }

    // ---- P2: tree; deep levels via conflict-free vector reads (R3 layout) ----
    {
        const int r0 = wave * 8;
        for (int rr = 0; rr < 8; ++rr) {
            const int row = r0 + rr;
            const int rowb = row << 10;
            const int x8 = swz8(row);
            float P = 1.f;
#pragma unroll
            for (int d = 0; d < 6; ++d) {
                int slot = (1 << d) + (lane >> (6 - d));   // gate (1<<d)-1 + ...
                float g = bf2f(sG[rowb + (slot ^ x8)]);
                int bit = (lane >> (5 - d)) & 1;
                P *= bit ? (1.f - g) : g;
            }
            // level 6: gate 63+lane (u16)
            float g6 = bf2f(sG[rowb + ((64 + lane) ^ x8)]);
            float va = P * g6, vb = P - va;
            // level 7: gates 127+2L,128+2L (b32, coalesced)
            unsigned w7 = *(const unsigned*)(sG + rowb + ((128 + 2 * lane) ^ x8));
            float v4[4];
            {
                float ga = bf2f((ushortT)w7), gbv = bf2f((ushortT)(w7 >> 16));
                v4[0] = va * ga;  v4[1] = va - v4[0];
                v4[2] = vb * gbv; v4[3] = vb - v4[2];
            }
            // level 8: gates 255+4L..+4 (b64, coalesced)
            const unsigned* p8 = (const unsigned*)(sG + rowb + ((256 + 4 * lane) ^ x8));
            unsigned w8a = p8[0], w8b = p8[1];
            float v8[8];
            {
                float h0 = bf2f((ushortT)w8a), h1 = bf2f((ushortT)(w8a >> 16));
                float h2 = bf2f((ushortT)w8b), h3 = bf2f((ushortT)(w8b >> 16));
                v8[0] = v4[0] * h0; v8[1] = v4[0] - v8[0];
                v8[2] = v4[1] * h1; v8[3] = v4[1] - v8[2];
                v8[4] = v4[2] * h2; v8[5] = v4[2] - v8[4];
                v8[6] = v4[3] * h3; v8[7] = v4[3] - v8[6];
            }
            // level 9: gates 511+8L..+8 (b128, lane->consecutive 16B slots)
            bf16x8 g9 = *(const bf16x8*)(sG + rowb + ((512 + 8 * lane) ^ x8));
            float v16[16];
#pragma unroll
            for (int t = 0; t < 8; ++t) {
                float g = bf2f((ushortT)g9[t]);
                float a = v8[t] * g;
                v16[2 * t] = a;
                v16[2 * t + 1] = v8[t] - a;
            }
            // leaves: block 2L -> slot L^x; block 2L+1 -> 64+(L^x); both b128
            // writes stride-16B conflict-free; row-local => in-place safe.
            union { unsigned u[4]; bf16x8 v; } q0, q1;
#pragma unroll
            for (int t = 0; t < 4; ++t) q0.u[t] = pkbf(v16[2 * t], v16[2 * t + 1]);
#pragma unroll
            for (int t = 0; t < 4; ++t) q1.u[t] = pkbf(v16[8 + 2 * t], v16[9 + 2 * t]);
            int a0u = rowb + ((lane << 3) ^ x8);
            *(bf16x8*)(sG + a0u) = q0.v;
            *(bf16x8*)(sG + a0u + 512) = q1.v;
        }
    }
    __syncthreads();

    // ---- P3: out = leaf @ z^T; 32 tiles of 128n x 32k, same 2-phase pipe ----
    {
        const int rowA = wr * 16 + l15;
        const int rowbA = rowA << 10;
        const int xA8 = swz8(rowA);
        // prologue: stage tile 0 into buf 0
#pragma unroll
        for (int r = 0; r < 2; ++r) {
            int e = wave * 2 + r;
            gl2lds16(zS + (size_t)(e * 16) * 1024, &sS[0][e * 512]);
        }
        __syncthreads();

        f32x4 acc[4] = {};
        for (int g = 0; g < 8; ++g) {
#pragma unroll
            for (int s = 0; s < 4; ++s) {
                int t = g * 4 + s;
                if (t < 31) {
                    int k1 = (t + 1) << 5;
#pragma unroll
                    for (int r = 0; r < 2; ++r) {
                        int e = wave * 2 + r;
                        gl2lds16(zS + (size_t)(e * 16) * 1024 + k1,
                                 &sS[(s & 1) ^ 1][e * 512]);
                    }
                }
                int b = 4 * t + quad;  // leaf block index for this lane's A-frag
                int us = ((b & 1) << 9) + ((((b >> 1) << 3)) ^ xA8);
                bf16x8 a0 = *(const bf16x8*)(sG + rowbA + us);
                __builtin_amdgcn_s_setprio(1);
#pragma unroll
                for (int j = 0; j < 4; ++j) {
                    bf16x8 b0 = *(const bf16x8*)(&sS[s & 1][(wc * 64 + j * 16 + l15) * 32 +
                                                           quad * 8]);
                    acc[j] = __builtin_amdgcn_mfma_f32_16x16x32_bf16(a0, b0, acc[j], 0, 0, 0);
                }
                __builtin_amdgcn_s_setprio(0);
                __syncthreads();
            }
        }
        const int gm = bm + wr * 16 + quad * 4;
#pragma unroll
        for (int j = 0; j < 4; ++j) {
            int gn = wc * 64 + j * 16 + l15;
#pragma unroll
            for (int r = 0; r < 4; ++r)
                out[(size_t)(gm + r) * OUTF + gn] = acc[j][r];
        }
    }
}

// ---------------- launch ----------------
extern "C" void kernel_launch(void* const* d_in, const int* in_sizes, int n_in,
                              void* d_out, int out_size, void* d_ws, size_t ws_size,
                              hipStream_t stream) {
    const float* x  = (const float*)d_in[0];   // 16384 x 256
    const float* gw = (const float*)d_in[1];   // 256 x 1023
    const float* gb = (const float*)d_in[2];   // 1023
    const float* z  = (const float*)d_in[3];   // 128 x 1024
    float* out = (float*)d_out;                // 16384 x 128

    char* ws = (char*)d_ws;
    ushortT* gwT = (ushortT*)(ws + 0);       // 524,288 B
    ushortT* zh  = (ushortT*)(ws + 524288);  // 262,144 B
    float*   gbp = (float*)  (ws + 786432);  //   4,096 B (total < 1 MB)

    k_prep<<<129, 256, 0, stream>>>(gw, gb, z, gwT, gbp, zh);
    k_mega<<<512, 256, 0, stream>>>(x, gwT, gbp, zh, out);
}